// Round 5
// baseline (677.213 us; speedup 1.0000x reference)
//
#include <hip/hip_runtime.h>

typedef __bf16 bf16;
typedef __bf16 bf16x4 __attribute__((ext_vector_type(4)));
typedef __bf16 bf16x8 __attribute__((ext_vector_type(8)));
typedef float f32x4 __attribute__((ext_vector_type(4)));

#define S_LEN 2048
#define HID   3584
#define NHEADS 16
#define NKVH   8
#define HDIM   256
#define QKV_O  8192   // (16 + 2*8) * 256
#define O_IN   4096   // 16 * 256

typedef const __attribute__((address_space(1))) void* gp_t;
typedef __attribute__((address_space(3))) void* sp_t;

__device__ __forceinline__ void async16(const void* g, void* s) {
  __builtin_amdgcn_global_load_lds((gp_t)g, (sp_t)s, 16, 0, 0);
}

__device__ __forceinline__ f32x4 mfma16(bf16x8 a, bf16x8 b, f32x4 c) {
  return __builtin_amdgcn_mfma_f32_16x16x32_bf16(a, b, c, 0, 0, 0);
}

// ---------------- fp32 -> bf16 cast (4 elems/thread) ----------------
__global__ __launch_bounds__(256) void cast_kernel(const float* __restrict__ in,
                                                   bf16* __restrict__ out, int n4) {
  int i = blockIdx.x * 256 + threadIdx.x;
  if (i >= n4) return;
  f32x4 v = ((const f32x4*)in)[i];
  bf16x4 o = { (bf16)v[0], (bf16)v[1], (bf16)v[2], (bf16)v[3] };
  ((bf16x4*)out)[i] = o;
}

// ---------------- f32 add: out = a + b (4 elems/thread) ----------------
__global__ __launch_bounds__(256) void add_kernel(const float* __restrict__ a,
                                                  const float* __restrict__ b,
                                                  float* __restrict__ out, int n4) {
  int i = blockIdx.x * 256 + threadIdx.x;
  if (i >= n4) return;
  f32x4 x = ((const f32x4*)a)[i];
  f32x4 y = ((const f32x4*)b)[i];
  f32x4 z = { x[0] + y[0], x[1] + y[1], x[2] + y[2], x[3] + y[3] };
  ((f32x4*)out)[i] = z;
}

// ---------------- NT bf16 GEMM: C[M,N] OutT = A[M,K] * B[N,K]^T ----------------
// Round-3 structure (BK=32, XOR chunk swizzle, conflict-free) + compile-time K:
// KSTR/KLEN template constants let the compiler strength-reduce the 8 per-iter
// 64-bit address derivations into increments (R3 VALUBusy 57% vs m97's 43%) and
// unroll x2. BK=64 (R4) regressed via occupancy (VGPR 92, 2 blocks/CU) -- reverted.
template<int KSTR, int KLEN, typename OutT>
__global__ __launch_bounds__(256) void gemm_nt(const bf16* __restrict__ A, const bf16* __restrict__ B,
                                               OutT* __restrict__ C, int N) {
  __shared__ bf16 As[128 * 32];
  __shared__ bf16 Bs[128 * 32];
  int tid = threadIdx.x;
  int lane = tid & 63;
  int bm = blockIdx.y, bn = blockIdx.x;
  int w = tid >> 6, wm = w >> 1, wn = w & 1;
  int fr = lane & 15, fq = lane >> 4;
  int sr = tid >> 2;                        // staging row 0..63 (pass adds +64; (r+64)>>1 & 3 == (r>>1)&3)
  int sw = (sr >> 1) & 3;                   // row swizzle
  int scol = (((tid & 3) ^ sw) * 8);        // permuted GLOBAL k-chunk
  const bf16* Ag = A + (size_t)(bm * 128 + sr) * KSTR + scol;
  const bf16* Bg = B + (size_t)(bn * 128 + sr) * KSTR + scol;
  bf16* Asl = &As[sr * 32 + (tid & 3) * 8]; // lane-linear LDS dest (= base + lane*16B)
  bf16* Bsl = &Bs[sr * 32 + (tid & 3) * 8];
  int fsw = (fr >> 1) & 3;
  const bf16* Af = &As[(wm * 64 + fr) * 32 + (fq ^ fsw) * 8];
  const bf16* Bf = &Bs[(wn * 64 + fr) * 32 + (fq ^ fsw) * 8];
  f32x4 acc[4][4];
#pragma unroll
  for (int i = 0; i < 4; i++)
#pragma unroll
    for (int j = 0; j < 4; j++) { f32x4 z = {0.f, 0.f, 0.f, 0.f}; acc[i][j] = z; }
#pragma unroll 2
  for (int k0 = 0; k0 < KLEN; k0 += 32) {
    __syncthreads();
    async16(Ag + k0, Asl);
    async16(Ag + (size_t)64 * KSTR + k0, Asl + 64 * 32);
    async16(Bg + k0, Bsl);
    async16(Bg + (size_t)64 * KSTR + k0, Bsl + 64 * 32);
    __syncthreads();
    bf16x8 a[4], b[4];
#pragma unroll
    for (int t = 0; t < 4; t++) a[t] = *(const bf16x8*)(Af + t * 16 * 32);
#pragma unroll
    for (int t = 0; t < 4; t++) b[t] = *(const bf16x8*)(Bf + t * 16 * 32);
#pragma unroll
    for (int i = 0; i < 4; i++)
#pragma unroll
      for (int j = 0; j < 4; j++) acc[i][j] = mfma16(a[i], b[j], acc[i][j]);
  }
  int row0 = bm * 128 + wm * 64 + fq * 4;
  int col0 = bn * 128 + wn * 64 + fr;
#pragma unroll
  for (int i = 0; i < 4; i++)
#pragma unroll
    for (int j = 0; j < 4; j++)
#pragma unroll
      for (int r = 0; r < 4; r++)
        C[(size_t)(row0 + i * 16 + r) * N + col0 + j * 16] = (OutT)acc[i][j][r];
}

// ---------------- RMSNorm + RoPE + q-scale; one wave per (s, head); bf16 in ----------------
__global__ __launch_bounds__(256) void qk_norm_rope(const bf16* __restrict__ qkv,
                                                    const float* __restrict__ cosb,
                                                    const float* __restrict__ sinb,
                                                    const float* __restrict__ qw,
                                                    const float* __restrict__ kw,
                                                    bf16* __restrict__ qout,
                                                    bf16* __restrict__ kout) {
  int s = blockIdx.x;
  int lane = threadIdx.x & 63;
  int w = threadIdx.x >> 6;
  int d0 = lane * 4;
  int dr = d0 & 127;
  f32x4 cv = *(const f32x4*)(cosb + s * 128 + dr);
  f32x4 sv = *(const f32x4*)(sinb + s * 128 + dr);
  bool hi = lane >= 32;
#pragma unroll
  for (int r = 0; r < 6; r++) {
    int head = r * 4 + w;  // 0..23 : 16 q heads then 8 k heads
    const bf16* x = qkv + (size_t)s * QKV_O + head * HDIM + d0;
    bf16x4 vb = *(const bf16x4*)x;
    float v0 = (float)vb[0], v1 = (float)vb[1], v2 = (float)vb[2], v3 = (float)vb[3];
    float ss = v0 * v0 + v1 * v1 + v2 * v2 + v3 * v3;
#pragma unroll
    for (int off = 32; off > 0; off >>= 1) ss += __shfl_xor(ss, off);
    float scale = rsqrtf(ss * (1.0f / HDIM) + 1e-6f);
    bool isq = head < NHEADS;
    const float* wn = isq ? qw : kw;
    f32x4 wv = *(const f32x4*)(wn + d0);
    float y[4], o[4];
    y[0] = v0 * scale * (1.0f + wv[0]);
    y[1] = v1 * scale * (1.0f + wv[1]);
    y[2] = v2 * scale * (1.0f + wv[2]);
    y[3] = v3 * scale * (1.0f + wv[3]);
#pragma unroll
    for (int i = 0; i < 4; i++) {
      float py = __shfl_xor(y[i], 32);
      o[i] = hi ? (py * sv[i] + y[i] * cv[i]) : (y[i] * cv[i] - py * sv[i]);
    }
    float mult = isq ? 0.0625f : 1.0f;  // SCALING = 256^-0.5 folded into q
    bf16x4 ov = { (bf16)(o[0] * mult), (bf16)(o[1] * mult), (bf16)(o[2] * mult), (bf16)(o[3] * mult) };
    if (isq) *(bf16x4*)(qout + ((size_t)head * S_LEN + s) * HDIM + d0) = ov;
    else     *(bf16x4*)(kout + ((size_t)(head - NHEADS) * S_LEN + s) * HDIM + d0) = ov;
  }
}

// ---------------- V transpose: qkv bf16 [s][6144+h*256+d] -> vt bf16 [h][d][s] ----------------
__global__ __launch_bounds__(256) void v_transpose(const bf16* __restrict__ qkv, bf16* __restrict__ vt) {
  __shared__ float tile[64][65];
  int dt = blockIdx.x, st = blockIdx.y, h = blockIdx.z;
  int t = threadIdx.x;
  int d0 = dt * 64, s0 = st * 64;
#pragma unroll
  for (int i = 0; i < 16; i++) {
    int idx = i * 256 + t;
    int r = idx >> 6, c = idx & 63;  // r = s-offset, c = d-offset
    tile[r][c] = (float)qkv[(size_t)(s0 + r) * QKV_O + 6144 + h * HDIM + d0 + c];
  }
  __syncthreads();
#pragma unroll
  for (int i = 0; i < 16; i++) {
    int idx = i * 256 + t;
    int dr = idx >> 6, sc = idx & 63;  // dr = d-offset, sc = s-offset
    vt[((size_t)h * HDIM + d0 + dr) * S_LEN + s0 + sc] = (bf16)tile[sc][dr];
  }
}

// ---------------- Flash attention: 64 q-rows/block, Bk=32 ----------------
// Fixed-max softmax (softcap bounds s to [-50,50]; p=exp(s-30) always normal).
#define PSTRIDE 40  // pbuf row stride in bf16 (80 B): conflict-free, keeps 16B align
__global__ __launch_bounds__(256) void attn_kernel(const bf16* __restrict__ q,
                                                   const bf16* __restrict__ kx,
                                                   const bf16* __restrict__ vt,
                                                   bf16* __restrict__ aout) {
  __shared__ bf16 kt[32 * 256];          // K-tile [k'][d], row-rotation swizzled by k'*8 elems
  __shared__ bf16 vtile[256 * 32];       // V-tile [d][k'], XOR chunk swizzle on k'
  __shared__ bf16 pbuf[4][16 * PSTRIDE]; // per-wave P staging (C-layout -> A-layout)
  int h = blockIdx.x;
  int y = blockIdx.y;
  int qt = (y < 16) ? y : 47 - y;  // dispatch-balance pairing: CU gets qt + (31-qt)
  int kvh = h >> 1;                // GQA: q head h uses kv head h/2
  int tid = threadIdx.x;
  int lane = tid & 63, w = tid >> 6;
  int fr = lane & 15, fq = lane >> 4;
  int qs = qt * 64;
  bf16x8 qf[8];
  const bf16* qb = q + ((size_t)h * S_LEN + qs + w * 16 + fr) * HDIM + fq * 8;
#pragma unroll
  for (int i = 0; i < 8; i++) qf[i] = *(const bf16x8*)(qb + i * 32);
  f32x4 acc[16];
#pragma unroll
  for (int i = 0; i < 16; i++) { f32x4 z = {0.f, 0.f, 0.f, 0.f}; acc[i] = z; }
  float lsum[4] = {0.f, 0.f, 0.f, 0.f};
  // staging lane roles
  int krow = w * 2 + (lane >> 5);
  int kcolr = (lane & 31) * 8;
  const bf16* kg = kx + (size_t)kvh * S_LEN * HDIM;
  int vd = w * 16 + (lane >> 2);
  int vsw = (vd >> 1) & 3;                      // V XOR swizzle
  int vcl = (lane & 3) * 8;                     // LDS chunk slot (lane-linear)
  int vcg = (((lane & 3) ^ vsw) * 8);           // permuted global chunk
  const bf16* vg = vt + (size_t)kvh * HDIM * S_LEN;
  // swizzled fragment read bases: row r of kt holds K[r][(c + r*8) & 255] at col c
  int rot0 = (fq * 8 - fr * 8) & 255;
  int rot1 = (fq * 8 - fr * 8 - 128) & 255;
  const bf16* kt0 = &kt[fr * 256];
  const bf16* kt1 = &kt[(16 + fr) * 256];
  int fsw = (fr >> 1) & 3;
  int kmax = qs + 64;
  for (int k0 = 0; k0 < kmax; k0 += 32) {
    __syncthreads();
#pragma unroll
    for (int p = 0; p < 4; p++) {
      int r = p * 8 + krow;
      int gc = (kcolr + r * 8) & 255;
      async16(kg + (size_t)(k0 + r) * HDIM + gc, &kt[r * 256 + kcolr]);
      int d = p * 64 + vd;
      async16(vg + (size_t)d * S_LEN + k0 + vcg, &vtile[d * 32 + vcl]);
    }
    __syncthreads();
    // QK^T for two 16-col score tiles
    f32x4 s0 = {0.f, 0.f, 0.f, 0.f}, s1 = {0.f, 0.f, 0.f, 0.f};
#pragma unroll
    for (int kk = 0; kk < 8; kk++) {
      bf16x8 b0 = *(const bf16x8*)(kt0 + ((kk * 32 + rot0) & 255));
      bf16x8 b1 = *(const bf16x8*)(kt1 + ((kk * 32 + rot1) & 255));
      s0 = mfma16(qf[kk], b0, s0);
      s1 = mfma16(qf[kk], b1, s1);
    }
    // softcap + causal mask + fixed-max exp: p = exp2(28.853901 - 144.26950/(u+1)),
    // u = exp2(x * 0.04*log2e)
#pragma unroll
    for (int reg = 0; reg < 4; reg++) {
      int rowg = qs + w * 16 + fq * 4 + reg;
      float u0 = __builtin_amdgcn_exp2f(0.057707802f * s0[reg]);
      float u1 = __builtin_amdgcn_exp2f(0.057707802f * s1[reg]);
      float p0 = __builtin_amdgcn_exp2f(28.853901f - 144.26950f * __builtin_amdgcn_rcpf(u0 + 1.0f));
      float p1 = __builtin_amdgcn_exp2f(28.853901f - 144.26950f * __builtin_amdgcn_rcpf(u1 + 1.0f));
      p0 = (k0 + fr <= rowg) ? p0 : 0.0f;
      p1 = (k0 + 16 + fr <= rowg) ? p1 : 0.0f;
      lsum[reg] += p0 + p1;
      pbuf[w][(fq * 4 + reg) * PSTRIDE + fr] = (bf16)p0;
      pbuf[w][(fq * 4 + reg) * PSTRIDE + 16 + fr] = (bf16)p1;
    }
    // PV: P in A-layout (same-wave LDS round trip), V^T b128 fragments (swizzled)
    bf16x8 pf = *(const bf16x8*)&pbuf[w][fr * PSTRIDE + fq * 8];
#pragma unroll
    for (int ct = 0; ct < 16; ct++) {
      bf16x8 vf = *(const bf16x8*)&vtile[(ct * 16 + fr) * 32 + (fq ^ fsw) * 8];
      acc[ct] = mfma16(pf, vf, acc[ct]);
    }
  }
  // final l reduction over the 16 fr lanes of each row, then divide
  float rl[4];
#pragma unroll
  for (int reg = 0; reg < 4; reg++) {
    float l = lsum[reg];
    l += __shfl_xor(l, 1);
    l += __shfl_xor(l, 2);
    l += __shfl_xor(l, 4);
    l += __shfl_xor(l, 8);
    rl[reg] = 1.0f / l;
  }
#pragma unroll
  for (int ct = 0; ct < 16; ct++)
#pragma unroll
    for (int reg = 0; reg < 4; reg++)
      aout[(size_t)(qs + w * 16 + fq * 4 + reg) * O_IN + h * HDIM + ct * 16 + fr] =
          (bf16)(acc[ct][reg] * rl[reg]);
}

extern "C" void kernel_launch(void* const* d_in, const int* in_sizes, int n_in,
                              void* d_out, int out_size, void* d_ws, size_t ws_size,
                              hipStream_t stream) {
  const float* hidden = (const float*)d_in[0];
  const float* cosb   = (const float*)d_in[1];
  const float* sinb   = (const float*)d_in[2];
  const float* wqkv   = (const float*)d_in[7];
  const float* wo     = (const float*)d_in[8];
  const float* qnw    = (const float*)d_in[9];
  const float* knw    = (const float*)d_in[10];
  float* out = (float*)d_out;
  char* ws = (char*)d_ws;
  bf16*  h_bf    = (bf16*)(ws + 0);          // 2048*3584*2   = 14,680,064
  bf16*  wqkv_bf = (bf16*)(ws + 14680064);   // 8192*3584*2   = 58,720,256 (dead after QKV gemm)
  float* oprt1   = (float*)(ws + 14680064);  // 2048*3584*4   = 29,360,128 (reuses wqkv_bf)
  float* oprt2   = (float*)(ws + 44040192);  // 2048*3584*4   = 29,360,128 (reuses wqkv_bf)
  bf16*  wo_bf   = (bf16*)(ws + 73400320);   // 3584*4096*2   = 29,360,128
  bf16*  qkv     = (bf16*)(ws + 102760448);  // 2048*8192*2   = 33,554,432 (bf16 now)
  bf16*  qb      = (bf16*)(ws + 169869312);  // 16*2048*256*2 = 16,777,216
  bf16*  kb      = (bf16*)(ws + 186646528);  // 8*2048*256*2  =  8,388,608
  bf16*  vtb     = (bf16*)(ws + 195035136);  // 8*256*2048*2  =  8,388,608
  bf16*  attnb   = (bf16*)(ws + 203423744);  // 2048*4096*2   = 16,777,216

  cast_kernel<<<7168, 256, 0, stream>>>(hidden, h_bf, 1835008);
  cast_kernel<<<28672, 256, 0, stream>>>(wqkv, wqkv_bf, 7340032);
  cast_kernel<<<14336, 256, 0, stream>>>(wo, wo_bf, 3670016);
  gemm_nt<3584, 3584, bf16><<<dim3(64, 16), 256, 0, stream>>>(h_bf, wqkv_bf, qkv, 8192);
  qk_norm_rope<<<2048, 256, 0, stream>>>(qkv, cosb, sinb, qnw, knw, qb, kb);
  v_transpose<<<dim3(4, 32, 8), 256, 0, stream>>>(qkv, vtb);
  attn_kernel<<<dim3(16, 32), 256, 0, stream>>>(qb, kb, vtb, attnb);
  // O-proj split-K x2 (grid 448 -> 896 blocks for occupancy), deterministic add
  gemm_nt<4096, 2048, float><<<dim3(28, 16), 256, 0, stream>>>(attnb, wo_bf, oprt1, 3584);
  gemm_nt<4096, 2048, float><<<dim3(28, 16), 256, 0, stream>>>(attnb + 2048, wo_bf + 2048, oprt2, 3584);
  add_kernel<<<7168, 256, 0, stream>>>(oprt1, oprt2, out, 1835008);
}